// Round 4
// baseline (1500.631 us; speedup 1.0000x reference)
//
#include <hip/hip_runtime.h>
#include <hip/hip_bf16.h>

// ---------------- problem constants ----------------
#define NTT 128
#define NXX 512
#define NB  2
#define NPN (NTT*NXX)        // 65536 nodes per batch
#define NNODES (NB*NPN)      // 131072
#define EPB 520452           // edges per batch
#define NE  (NB*EPB)         // 1040904 total edges
#define OUTTOT (NNODES + 3*NE)   // 3253784

// ---------------- workspace layout (float offsets) ----------------
#define H_OFF    0u
#define PS_OFF   4194304u
#define Q_OFF    8388608u
#define SG_OFF   12582912u
#define UF_OFF   12648448u
#define DUX_OFF  12713984u
#define DUT_OFF  12779520u
#define WF_OFF   12845056u
#define FLAG_OFF 12922248u
#define WS_NEED_FLOATS 12922252u   // ~51.69 MB (proven available: >=51.68 MB)

// f32 weight sub-offsets inside wf
#define IN_W 0
#define IN_B 64
#define MW1  128      // (3,130,64) per-layer stride 8320
#define MB1  25088    // (3,64)
#define MW2  25280    // (3,64,64) stride 4096
#define MB2  37568
#define GW1  37760    // (3,7,64) stride 448
#define GB1  39104
#define GW2  39296    // (3,64)
#define GB2  39488    // (3) padded to 4
#define UW1  39492    // (3,128,64) stride 8192
#define UB1  64068
#define UW2  64260    // (3,64,64) stride 4096
#define UB2  76548
#define LNG  76740
#define LNB  76932
#define OUTW 77124
#define OUTB 77188

typedef __hip_bfloat16 bf16;

__device__ __forceinline__ float b2f(bf16 x){ return __bfloat162float(x); }
__device__ __forceinline__ float geluf(float v){
  return 0.5f*v*(1.0f + erff(v*0.7071067811865476f));
}
// dtype-agnostic input load / output store (isf: 1 = float32, 0 = bf16)
__device__ __forceinline__ float ldf(const void* p, long i, int isf){
  return isf ? ((const float*)p)[i] : b2f(((const bf16*)p)[i]);
}
__device__ __forceinline__ void stf(void* p, long i, float v, int isf){
  if (isf) ((float*)p)[i] = v;
  else ((bf16*)p)[i] = __float2bfloat16(v);
}

// ---------------- dtype sniff: bf16-interpret first 128 halves of u ----------------
__global__ void k_sniff(const void* __restrict__ u, int* __restrict__ flag)
{
  int tid = threadIdx.x;   // 64 threads
  unsigned w = ((const unsigned*)u)[tid];
  int bad = 0;
  #pragma unroll
  for (int h=0; h<2; h++){
    unsigned bits = ((h ? (w>>16) : (w & 0xffffu)) << 16);
    float v = __uint_as_float(bits);
    if (!(v == v) || fabsf(v) > 64.0f) bad = 1;   // NaN/Inf or implausibly large
  }
  unsigned long long anybad = __ballot(bad);
  if (tid == 0) *flag = (anybad != 0ull) ? 1 : 0;  // garbage halves => underlying f32
}

// ---------------- diagnostic fallback ----------------
__global__ void __launch_bounds__(256) k_encode(bf16* __restrict__ out, float val)
{
  int i = blockIdx.x*256 + threadIdx.x;
  if (i < OUTTOT) out[i] = __float2bfloat16(i == 0 ? val : 0.0f);
}

// ---------------- convert all weights to f32 scratch ----------------
struct WArgs { const void* p[18]; int cnt[18]; int off[18]; };

__global__ void __launch_bounds__(256) k_conv(WArgs a, float* __restrict__ wf,
                                              const int* __restrict__ flag)
{
  int y = blockIdx.y;
  int i = blockIdx.x*256 + threadIdx.x;
  int isf = *flag;
  if (i < a.cnt[y]) wf[a.off[y] + i] = ldf(a.p[y], i, isf);
}

// ---------------- node features for one batch ----------------
__global__ void __launch_bounds__(256) k_feat(
    const void* __restrict__ ub, long ubase, const int* __restrict__ flag,
    float* __restrict__ uf, float* __restrict__ dux, float* __restrict__ dut)
{
  int i = blockIdx.x*256 + threadIdx.x;   // [0, NPN)
  int isf = *flag;
  int t = i / NXX, n = i % NXX;
  float uc = ldf(ub, ubase + i, isf);
  uf[i] = uc;
  float dxv;
  if (n == 0)          dxv = (ldf(ub, ubase + t*NXX + 1, isf) - uc) * 512.0f;
  else if (n == NXX-1) dxv = (uc - ldf(ub, ubase + t*NXX + NXX-2, isf)) * 512.0f;
  else                 dxv = (ldf(ub, ubase + t*NXX + n+1, isf) - ldf(ub, ubase + t*NXX + n-1, isf)) * 256.0f;
  dux[i] = dxv;
  float dtv;
  if (t == 0)          dtv = (ldf(ub, ubase + NXX + n, isf) - uc) * 128.0f;
  else if (t == NTT-1) dtv = (uc - ldf(ub, ubase + (NTT-2)*NXX + n, isf)) * 128.0f;
  else                 dtv = (ldf(ub, ubase + (t+1)*NXX + n, isf) - ldf(ub, ubase + (t-1)*NXX + n, isf)) * 64.0f;
  dut[i] = dtv;
}

// ---------------- h0 = u*in_w + in_b ----------------
__global__ void __launch_bounds__(256) k_inith(
    const float* __restrict__ uf, const float* __restrict__ wf, float* __restrict__ h)
{
  int idx = blockIdx.x*256 + threadIdx.x;
  int i = idx >> 6, c = idx & 63;
  h[idx] = uf[i]*wf[IN_W + c] + wf[IN_B + c];
}

// ---------------- phase A: PS = h@W1a, Q = h@W1b ----------------
__global__ void __launch_bounds__(256) k_A(
    const float* __restrict__ h, const float* __restrict__ w1l,
    float* __restrict__ PS, float* __restrict__ Q)
{
  int i = blockIdx.x*256 + threadIdx.x;
  const float4* hr = (const float4*)(h + (size_t)i*64);
  float acc[64];
  #pragma unroll
  for (int c=0;c<64;c++) acc[c]=0.f;
  for (int kb=0; kb<16; kb+=2){
    float4 v0 = hr[kb], v1 = hr[kb+1];
    float xs[8] = {v0.x,v0.y,v0.z,v0.w,v1.x,v1.y,v1.z,v1.w};
    #pragma unroll
    for (int j=0;j<8;j++){
      const float* wr = w1l + (kb*4+j)*64;
      #pragma unroll
      for (int c=0;c<64;c++) acc[c] = fmaf(xs[j], wr[c], acc[c]);
    }
  }
  float4* Pr = (float4*)(PS + (size_t)i*64);
  #pragma unroll
  for (int q=0;q<16;q++) Pr[q] = make_float4(acc[4*q],acc[4*q+1],acc[4*q+2],acc[4*q+3]);
  #pragma unroll
  for (int c=0;c<64;c++) acc[c]=0.f;
  for (int kb=0; kb<16; kb+=2){
    float4 v0 = hr[kb], v1 = hr[kb+1];
    float xs[8] = {v0.x,v0.y,v0.z,v0.w,v1.x,v1.y,v1.z,v1.w};
    #pragma unroll
    for (int j=0;j<8;j++){
      const float* wr = w1l + (64 + kb*4+j)*64;
      #pragma unroll
      for (int c=0;c<64;c++) acc[c] = fmaf(xs[j], wr[c], acc[c]);
    }
  }
  float4* Qr = (float4*)(Q + (size_t)i*64);
  #pragma unroll
  for (int q=0;q<16;q++) Qr[q] = make_float4(acc[4*q],acc[4*q+1],acc[4*q+2],acc[4*q+3]);
}

// ---------------- phase B: edges (wave per dst node, lane = channel) ----------------
__global__ void __launch_bounds__(256) k_B(
    float* __restrict__ PS, const float* __restrict__ Q,
    const float* __restrict__ uf, const float* __restrict__ dux, const float* __restrict__ dut,
    const float* __restrict__ wf, int l,
    float* __restrict__ sg, void* __restrict__ dout, long gbase,
    const int* __restrict__ flag)
{
  constexpr float DXF = 1.0f/512.0f, DTF = 1.0f/128.0f;
  constexpr int   DTKa[8] = {-1,1,0,0,-1,-1,1,1};
  constexpr int   DNKa[8] = {0,0,-1,1,-1,1,-1,1};
  constexpr float EDXa[8] = {0.f,0.f,-DXF,DXF,-DXF,DXF,-DXF,DXF};
  constexpr float EDTa[8] = {-DTF,DTF,0.f,0.f,-DTF,-DTF,DTF,DTF};
  constexpr int   BASEa[8]= {0,65024,130048,195456,260864,325761,390658,455555};
  constexpr int   TLOa[8] = {1,0,0,0,1,1,0,0};
  constexpr int   NLOa[8] = {0,0,1,0,1,0,1,0};
  constexpr int   NCNa[8] = {512,512,511,511,511,511,511,511};

  int lane = threadIdx.x & 63;
  int i = blockIdx.x*4 + (threadIdx.x >> 6);
  int isf = *flag;
  int t = i / NXX, n = i % NXX;

  const float* gw1 = wf + GW1 + l*448;
  float Pi = PS[(size_t)i*64 + lane];
  float u_i = uf[i], dxi = dux[i], dti = dut[i];
  float g0 = gw1[0*64+lane], g1 = gw1[1*64+lane], g2 = gw1[2*64+lane];
  float g3 = gw1[3*64+lane], g4 = gw1[4*64+lane], g5 = gw1[5*64+lane];
  float g6 = gw1[6*64+lane];
  float gb1v = wf[GB1 + l*64 + lane];
  float gw2v = wf[GW2 + l*64 + lane];
  float gb2v = wf[GB2 + l];
  const float* w1l = wf + MW1 + l*8320;
  float w128 = w1l[128*64+lane], w129 = w1l[129*64+lane];
  float mb1v = wf[MB1 + l*64 + lane];

  float Sacc = 0.f, sgacc = 0.f;
  #pragma unroll
  for (int k=0;k<8;k++){
    int ts = t - DTKa[k], ns = n - DNKa[k];
    if (ts >= 0 && ts < NTT && ns >= 0 && ns < NXX){
      int j = ts*NXX + ns;
      float u_j = uf[j], dxj = dux[j], dtj = dut[j];
      float Qj = Q[(size_t)j*64 + lane];
      float hg = gb1v;
      hg = fmaf(u_i, g0, hg);
      hg = fmaf(u_j, g1, hg);
      hg = fmaf(fabsf(u_i - u_j), g2, hg);
      hg = fmaf(dxi, g3, hg);
      hg = fmaf(dxj, g4, hg);
      hg = fmaf(dti, g5, hg);
      hg = fmaf(dtj, g6, hg);
      float gg = geluf(hg) * gw2v;
      #pragma unroll
      for (int o=32;o;o>>=1) gg += __shfl_xor(gg, o);
      float gate = 1.0f/(1.0f + __expf(-(gg + gb2v)));
      float pre = Pi + Qj + EDXa[k]*w128 + EDTa[k]*w129 + mb1v;
      Sacc = fmaf(gate, geluf(pre), Sacc);
      sgacc += gate;
      if (lane == 0){
        long eid = gbase + BASEa[k] + (ts - TLOa[k])*NCNa[k] + (ns - NLOa[k]);
        stf(dout, eid, gate, isf);
      }
    }
  }
  PS[(size_t)i*64 + lane] = Sacc;
  if (lane == 0) sg[i] = sgacc;
}

// ---------------- phase C1: agg = S@W2 + sg*b2, in place in PS ----------------
__global__ void __launch_bounds__(256) k_C1(
    float* __restrict__ PS, const float* __restrict__ sg,
    const float* __restrict__ wf, int l)
{
  int i = blockIdx.x*256 + threadIdx.x;
  const float* w2l = wf + MW2 + l*4096;
  const float* b2l = wf + MB2 + l*64;
  const float4* Sr = (const float4*)(PS + (size_t)i*64);
  float sgi = sg[i];
  float acc[64];
  #pragma unroll
  for (int c=0;c<64;c++) acc[c] = sgi * b2l[c];
  for (int kb=0; kb<16; kb+=2){
    float4 v0 = Sr[kb], v1 = Sr[kb+1];
    float xs[8] = {v0.x,v0.y,v0.z,v0.w,v1.x,v1.y,v1.z,v1.w};
    #pragma unroll
    for (int j=0;j<8;j++){
      const float* wr = w2l + (kb*4+j)*64;
      #pragma unroll
      for (int c=0;c<64;c++) acc[c] = fmaf(xs[j], wr[c], acc[c]);
    }
  }
  float4* ar = (float4*)(PS + (size_t)i*64);
  #pragma unroll
  for (int q=0;q<16;q++) ar[q] = make_float4(acc[4*q],acc[4*q+1],acc[4*q+2],acc[4*q+3]);
}

// ---------------- phase C2: hid = gelu([h,agg]@U1 + b1) -> Q ----------------
__global__ void __launch_bounds__(256) k_C2(
    const float* __restrict__ h, const float* __restrict__ agg,
    const float* __restrict__ wf, int l, float* __restrict__ hid)
{
  int i = blockIdx.x*256 + threadIdx.x;
  const float* u1l = wf + UW1 + l*8192;
  const float* b1l = wf + UB1 + l*64;
  const float4* hr = (const float4*)(h + (size_t)i*64);
  const float4* ar = (const float4*)(agg + (size_t)i*64);
  float acc[64];
  #pragma unroll
  for (int c=0;c<64;c++) acc[c] = b1l[c];
  for (int kb=0; kb<16; kb+=2){
    float4 v0 = hr[kb], v1 = hr[kb+1];
    float xs[8] = {v0.x,v0.y,v0.z,v0.w,v1.x,v1.y,v1.z,v1.w};
    #pragma unroll
    for (int j=0;j<8;j++){
      const float* wr = u1l + (kb*4+j)*64;
      #pragma unroll
      for (int c=0;c<64;c++) acc[c] = fmaf(xs[j], wr[c], acc[c]);
    }
  }
  for (int kb=0; kb<16; kb+=2){
    float4 v0 = ar[kb], v1 = ar[kb+1];
    float xs[8] = {v0.x,v0.y,v0.z,v0.w,v1.x,v1.y,v1.z,v1.w};
    #pragma unroll
    for (int j=0;j<8;j++){
      const float* wr = u1l + (64 + kb*4+j)*64;
      #pragma unroll
      for (int c=0;c<64;c++) acc[c] = fmaf(xs[j], wr[c], acc[c]);
    }
  }
  float4* hd = (float4*)(hid + (size_t)i*64);
  #pragma unroll
  for (int q=0;q<16;q++){
    float4 o;
    o.x = geluf(acc[4*q+0]); o.y = geluf(acc[4*q+1]);
    o.z = geluf(acc[4*q+2]); o.w = geluf(acc[4*q+3]);
    hd[q] = o;
  }
}

// ---------------- phase C3: upd + residual + LN (+ out proj on LAST) ----------------
template<int LAST>
__global__ void __launch_bounds__(256) k_C3(
    const float* __restrict__ hid, float* __restrict__ hio,
    const float* __restrict__ wf, int l,
    void* __restrict__ dout, long obase, const int* __restrict__ flag)
{
  int i = blockIdx.x*256 + threadIdx.x;
  const float* u2l = wf + UW2 + l*4096;
  const float* b2l = wf + UB2 + l*64;
  const float* lng = wf + LNG + l*64;
  const float* lnb = wf + LNB + l*64;
  const float4* xr = (const float4*)(hid + (size_t)i*64);
  float acc[64];
  #pragma unroll
  for (int c=0;c<64;c++) acc[c] = b2l[c];
  for (int kb=0; kb<16; kb+=2){
    float4 v0 = xr[kb], v1 = xr[kb+1];
    float xs[8] = {v0.x,v0.y,v0.z,v0.w,v1.x,v1.y,v1.z,v1.w};
    #pragma unroll
    for (int j=0;j<8;j++){
      const float* wr = u2l + (kb*4+j)*64;
      #pragma unroll
      for (int c=0;c<64;c++) acc[c] = fmaf(xs[j], wr[c], acc[c]);
    }
  }
  const float4* hr = (const float4*)(hio + (size_t)i*64);
  #pragma unroll
  for (int q=0;q<16;q++){
    float4 v = hr[q];
    acc[4*q+0] += v.x; acc[4*q+1] += v.y; acc[4*q+2] += v.z; acc[4*q+3] += v.w;
  }
  float m = 0.f;
  #pragma unroll
  for (int c=0;c<64;c++) m += acc[c];
  m *= (1.0f/64.0f);
  float var = 0.f;
  #pragma unroll
  for (int c=0;c<64;c++){ float d = acc[c]-m; var = fmaf(d,d,var); }
  var *= (1.0f/64.0f);
  float inv = 1.0f/sqrtf(var + 1e-5f);
  if (LAST){
    float o = wf[OUTB];
    #pragma unroll
    for (int c=0;c<64;c++){
      float hn = (acc[c]-m)*inv*lng[c] + lnb[c];
      o = fmaf(hn, wf[OUTW + c], o);
    }
    stf(dout, obase + i, o, *flag);
  } else {
    float4* ho = (float4*)(hio + (size_t)i*64);
    #pragma unroll
    for (int q=0;q<16;q++){
      float4 v;
      v.x = (acc[4*q+0]-m)*inv*lng[4*q+0] + lnb[4*q+0];
      v.y = (acc[4*q+1]-m)*inv*lng[4*q+1] + lnb[4*q+1];
      v.z = (acc[4*q+2]-m)*inv*lng[4*q+2] + lnb[4*q+2];
      v.w = (acc[4*q+3]-m)*inv*lng[4*q+3] + lnb[4*q+3];
      ho[q] = v;
    }
  }
}

// ---------------- host launcher ----------------
extern "C" void kernel_launch(void* const* d_in, const int* in_sizes, int n_in,
                              void* d_out, int out_size, void* d_ws, size_t ws_size,
                              hipStream_t stream)
{
  if (ws_size < (size_t)WS_NEED_FLOATS * 4ull) {
    k_encode<<<(OUTTOT+255)/256, 256, 0, stream>>>((bf16*)d_out, (float)ws_size);
    return;
  }

  float* ws  = (float*)d_ws;
  float* h   = ws + H_OFF;
  float* PS  = ws + PS_OFF;
  float* Qb  = ws + Q_OFF;
  float* sgb = ws + SG_OFF;
  float* uf  = ws + UF_OFF;
  float* dxb = ws + DUX_OFF;
  float* dtb = ws + DUT_OFF;
  float* wf  = ws + WF_OFF;
  int*  flag = (int*)(ws + FLAG_OFF);

  k_sniff<<<1, 64, 0, stream>>>(d_in[1], flag);

  WArgs wa;
  static const int cnts[18] = {64,64,24960,192,12288,192,1344,192,192,3,24576,192,12288,192,192,192,64,1};
  static const int offs[18] = {IN_W,IN_B,MW1,MB1,MW2,MB2,GW1,GB1,GW2,GB2,UW1,UB1,UW2,UB2,LNG,LNB,OUTW,OUTB};
  for (int k = 0; k < 18; k++){ wa.p[k] = d_in[4+k]; wa.cnt[k] = cnts[k]; wa.off[k] = offs[k]; }
  k_conv<<<dim3(98,18), 256, 0, stream>>>(wa, wf, flag);

  for (int b = 0; b < NB; b++){
    k_feat<<<256, 256, 0, stream>>>(d_in[1], (long)b*NPN, flag, uf, dxb, dtb);
    k_inith<<<16384, 256, 0, stream>>>(uf, wf, h);

    for (int l = 0; l < 3; l++){
      k_A<<<256, 256, 0, stream>>>(h, wf + MW1 + l*8320, PS, Qb);
      k_B<<<16384, 256, 0, stream>>>(PS, Qb, uf, dxb, dtb, wf, l,
          sgb, d_out, (long)NNODES + (long)l*NE + (long)b*EPB, flag);
      k_C1<<<256, 256, 0, stream>>>(PS, sgb, wf, l);
      k_C2<<<256, 256, 0, stream>>>(h, PS, wf, l, Qb);
      if (l < 2)
        k_C3<0><<<256, 256, 0, stream>>>(Qb, h, wf, l, d_out, (long)b*NPN, flag);
      else
        k_C3<1><<<256, 256, 0, stream>>>(Qb, h, wf, l, d_out, (long)b*NPN, flag);
    }
  }
}

// Round 5
// 697.146 us; speedup vs baseline: 2.1525x; 2.1525x over previous
//
#include <hip/hip_runtime.h>
#include <hip/hip_bf16.h>

// ---------------- problem constants ----------------
#define NTT 128
#define NXX 512
#define NB  2
#define NPN (NTT*NXX)        // 65536 nodes per batch
#define NNODES (NB*NPN)      // 131072
#define EPB 520452           // edges per batch
#define NE  (NB*EPB)         // 1040904 total edges
#define OUTTOT (NNODES + 3*NE)   // 3253784

// ---------------- workspace layout (float offsets) ----------------
#define H_OFF    0u
#define PS_OFF   4194304u
#define Q_OFF    8388608u
#define NF_OFF   12582912u   // float4 per node: (u, dux, dut, sg)
#define WF_OFF   12845056u
#define FLAG_OFF 12922248u
#define WS_NEED_FLOATS 12922252u   // identical to round-4 proven-OK footprint

// f32 weight sub-offsets inside wf
#define IN_W 0
#define IN_B 64
#define MW1  128      // (3,130,64) per-layer stride 8320
#define MB1  25088    // (3,64)
#define MW2  25280    // (3,64,64) stride 4096
#define MB2  37568
#define GW1  37760    // (3,7,64) stride 448
#define GB1  39104
#define GW2  39296    // (3,64)
#define GB2  39488    // (3)
#define UW1  39492    // (3,128,64) stride 8192
#define UB1  64068
#define UW2  64260    // (3,64,64) stride 4096
#define UB2  76548
#define LNG  76740
#define LNB  76932
#define OUTW 77124
#define OUTB 77188

typedef __hip_bfloat16 bf16;

__device__ __forceinline__ float b2f(bf16 x){ return __bfloat162float(x); }

__device__ __forceinline__ float fexp2(float x){
#if __has_builtin(__builtin_amdgcn_exp2f)
  return __builtin_amdgcn_exp2f(x);
#else
  return exp2f(x);
#endif
}
__device__ __forceinline__ float frcp(float x){
#if __has_builtin(__builtin_amdgcn_rcpf)
  return __builtin_amdgcn_rcpf(x);
#else
  return 1.0f/x;
#endif
}
__device__ __forceinline__ float frsq(float x){
#if __has_builtin(__builtin_amdgcn_rsqf)
  return __builtin_amdgcn_rsqf(x);
#else
  return rsqrtf(x);
#endif
}
// tanh-approx GELU, exp2-folded: gelu(v) = v * (1 - 1/(1+e^{2z})), z=0.79788456 v(1+0.044715 v^2)
__device__ __forceinline__ float gelu_t(float v){
  float vv = v*v;
  float w  = v*fmaf(vv, 0.1029445f, 2.3022080f);   // 2*log2(e)*0.79788456*(1, 0.044715)
  float r  = frcp(1.0f + fexp2(w));
  return fmaf(-v, r, v);
}
__device__ __forceinline__ float sigm(float x){
  return frcp(1.0f + fexp2(-1.44269504f*x));
}
// dtype-agnostic input load / output store (isf: 1 = float32, 0 = bf16)
__device__ __forceinline__ float ldf(const void* p, long i, int isf){
  return isf ? ((const float*)p)[i] : b2f(((const bf16*)p)[i]);
}
__device__ __forceinline__ void stf(void* p, long i, float v, int isf){
  if (isf) ((float*)p)[i] = v;
  else ((bf16*)p)[i] = __float2bfloat16(v);
}

// ---------------- dtype sniff ----------------
__global__ void k_sniff(const void* __restrict__ u, int* __restrict__ flag)
{
  int tid = threadIdx.x;
  unsigned w = ((const unsigned*)u)[tid];
  int bad = 0;
  #pragma unroll
  for (int h=0; h<2; h++){
    unsigned bits = ((h ? (w>>16) : (w & 0xffffu)) << 16);
    float v = __uint_as_float(bits);
    if (!(v == v) || fabsf(v) > 64.0f) bad = 1;
  }
  unsigned long long anybad = __ballot(bad);
  if (tid == 0) *flag = (anybad != 0ull) ? 1 : 0;
}

// ---------------- diagnostic fallback ----------------
__global__ void __launch_bounds__(256) k_encode(bf16* __restrict__ out, float val)
{
  int i = blockIdx.x*256 + threadIdx.x;
  if (i < OUTTOT) out[i] = __float2bfloat16(i == 0 ? val : 0.0f);
}

// ---------------- convert all weights to f32 scratch ----------------
struct WArgs { const void* p[18]; int cnt[18]; int off[18]; };

__global__ void __launch_bounds__(256) k_conv(WArgs a, float* __restrict__ wf,
                                              const int* __restrict__ flag)
{
  int y = blockIdx.y;
  int i = blockIdx.x*256 + threadIdx.x;
  int isf = *flag;
  if (i < a.cnt[y]) wf[a.off[y] + i] = ldf(a.p[y], i, isf);
}

// ---------------- node features: nf = (u, du/dx, du/dt, 0) ----------------
__global__ void __launch_bounds__(256) k_feat(
    const void* __restrict__ ub, long ubase, const int* __restrict__ flag,
    float4* __restrict__ nf)
{
  int i = blockIdx.x*256 + threadIdx.x;   // [0, NPN)
  int isf = *flag;
  int t = i >> 9, n = i & 511;
  float uc = ldf(ub, ubase + i, isf);
  float dxv;
  if (n == 0)          dxv = (ldf(ub, ubase + t*NXX + 1, isf) - uc) * 512.0f;
  else if (n == NXX-1) dxv = (uc - ldf(ub, ubase + t*NXX + NXX-2, isf)) * 512.0f;
  else                 dxv = (ldf(ub, ubase + t*NXX + n+1, isf) - ldf(ub, ubase + t*NXX + n-1, isf)) * 256.0f;
  float dtv;
  if (t == 0)          dtv = (ldf(ub, ubase + NXX + n, isf) - uc) * 128.0f;
  else if (t == NTT-1) dtv = (uc - ldf(ub, ubase + (NTT-2)*NXX + n, isf)) * 128.0f;
  else                 dtv = (ldf(ub, ubase + (t+1)*NXX + n, isf) - ldf(ub, ubase + (t-1)*NXX + n, isf)) * 64.0f;
  nf[i] = make_float4(uc, dxv, dtv, 0.0f);
}

// ---------------- k_init: h0 = u*in_w+in_b; P=h0@W1a, Q=h0@W1b (layer 0) ------
// 256 threads = 4 waves; wave w computes cols [16w,16w+16) for 64 nodes (lane=node)
__global__ void __launch_bounds__(256) k_init(
    const float4* __restrict__ nf, float* __restrict__ h,
    float* __restrict__ PS, float* __restrict__ Qb, const float* __restrict__ wf)
{
  int lane = threadIdx.x & 63;
  int cb = __builtin_amdgcn_readfirstlane((threadIdx.x >> 6) * 16);
  int node = blockIdx.x*64 + lane;
  float ui = nf[node].x;
  const float* w1 = wf + MW1;   // layer 0
  float accP[16], accQ[16];
  #pragma unroll
  for (int c=0;c<16;c++){ accP[c]=0.f; accQ[c]=0.f; }
  #pragma unroll 2
  for (int j=0;j<64;j++){
    float h0j = fmaf(ui, wf[IN_W+j], wf[IN_B+j]);
    const float* wp = w1 + j*64 + cb;
    const float* wq = w1 + (64+j)*64 + cb;
    #pragma unroll
    for (int c=0;c<16;c++){
      accP[c] = fmaf(h0j, wp[c], accP[c]);
      accQ[c] = fmaf(h0j, wq[c], accQ[c]);
    }
  }
  float* hrow = h + (size_t)node*64 + cb;
  float* prow = PS + (size_t)node*64 + cb;
  float* qrow = Qb + (size_t)node*64 + cb;
  #pragma unroll
  for (int q=0;q<4;q++){
    float4 hv;
    hv.x = fmaf(ui, wf[IN_W+cb+4*q+0], wf[IN_B+cb+4*q+0]);
    hv.y = fmaf(ui, wf[IN_W+cb+4*q+1], wf[IN_B+cb+4*q+1]);
    hv.z = fmaf(ui, wf[IN_W+cb+4*q+2], wf[IN_B+cb+4*q+2]);
    hv.w = fmaf(ui, wf[IN_W+cb+4*q+3], wf[IN_B+cb+4*q+3]);
    *(float4*)(hrow + 4*q) = hv;
    *(float4*)(prow + 4*q) = make_float4(accP[4*q],accP[4*q+1],accP[4*q+2],accP[4*q+3]);
    *(float4*)(qrow + 4*q) = make_float4(accQ[4*q],accQ[4*q+1],accQ[4*q+2],accQ[4*q+3]);
  }
}

// ---------------- phase B: edges (wave per dst node, lane = channel) ----------
__global__ void __launch_bounds__(256) k_B(
    float* __restrict__ PS, const float* __restrict__ Qb,
    const float4* __restrict__ nf, float* __restrict__ nfw,
    const float* __restrict__ wf, int l,
    void* __restrict__ dout, long gbase, const int* __restrict__ flag)
{
  constexpr int   DTKa[8] = {-1,1,0,0,-1,-1,1,1};
  constexpr int   DNKa[8] = {0,0,-1,1,-1,1,-1,1};
  constexpr float SXa[8]  = {0.f,0.f,-1.f,1.f,-1.f,1.f,-1.f,1.f};
  constexpr float STa[8]  = {-1.f,1.f,0.f,0.f,-1.f,-1.f,1.f,1.f};
  constexpr int   BASEa[8]= {0,65024,130048,195456,260864,325761,390658,455555};
  constexpr int   TLOa[8] = {1,0,0,0,1,1,0,0};
  constexpr int   NLOa[8] = {0,0,1,0,1,0,1,0};
  constexpr int   NCNa[8] = {512,512,511,511,511,511,511,511};

  int lane = threadIdx.x & 63;
  int iu = __builtin_amdgcn_readfirstlane(blockIdx.x*4 + (threadIdx.x >> 6));
  int isf = *flag;
  int tu = iu >> 9, nu = iu & 511;

  const float* gw1 = wf + GW1 + l*448;
  float Pi = PS[(size_t)iu*64 + lane];
  float4 fi = nf[iu];
  float g1 = gw1[1*64+lane], g2 = gw1[2*64+lane];
  float g4 = gw1[4*64+lane], g6 = gw1[6*64+lane];
  // a_i = gb1 + u_i*g0 + dux_i*g3 + dut_i*g5
  float a_i = wf[GB1 + l*64 + lane];
  a_i = fmaf(fi.x, gw1[0*64+lane], a_i);
  a_i = fmaf(fi.y, gw1[3*64+lane], a_i);
  a_i = fmaf(fi.z, gw1[5*64+lane], a_i);
  float gw2v = wf[GW2 + l*64 + lane];
  float gb2v = wf[GB2 + l];
  const float* w1l = wf + MW1 + l*8320;
  float ecA = w1l[128*64+lane] * (1.0f/512.0f);
  float ecB = w1l[129*64+lane] * (1.0f/128.0f);
  float baseP = Pi + wf[MB1 + l*64 + lane];

  // ---- phase 1: gate hidden + batched reduces ----
  float gg[8];
  #pragma unroll
  for (int k=0;k<8;k++){
    gg[k] = 0.f;
    int ts = tu - DTKa[k], ns = nu - DNKa[k];
    if (ts >= 0 && ts < NTT && ns >= 0 && ns < NXX){
      int j = ts*NXX + ns;
      float4 fj = nf[j];
      float hg = fmaf(fj.x, g1, a_i);
      hg = fmaf(fj.y, g4, hg);
      hg = fmaf(fj.z, g6, hg);
      hg = fmaf(fabsf(fi.x - fj.x), g2, hg);
      gg[k] = gelu_t(hg) * gw2v;
    }
  }
  #pragma unroll
  for (int o=32;o;o>>=1){
    #pragma unroll
    for (int k=0;k<8;k++) gg[k] += __shfl_xor(gg[k], o);
  }
  float gate[8];
  #pragma unroll
  for (int k=0;k<8;k++) gate[k] = sigm(gg[k] + gb2v);

  // ---- phase 2: gated message accumulation ----
  float Sacc = 0.f, sga = 0.f;
  #pragma unroll
  for (int k=0;k<8;k++){
    int ts = tu - DTKa[k], ns = nu - DNKa[k];
    if (ts >= 0 && ts < NTT && ns >= 0 && ns < NXX){
      int j = ts*NXX + ns;
      float Qj = Qb[(size_t)j*64 + lane];
      float pre = fmaf(SXa[k], ecA, fmaf(STa[k], ecB, baseP)) + Qj;
      Sacc = fmaf(gate[k], gelu_t(pre), Sacc);
      sga += gate[k];
      if (lane == 0){
        long eid = gbase + BASEa[k] + (ts - TLOa[k])*NCNa[k] + (ns - NLOa[k]);
        stf(dout, eid, gate[k], isf);
      }
    }
  }
  PS[(size_t)iu*64 + lane] = Sacc;
  if (lane == 0) nfw[4*iu + 3] = sga;
}

// ---------------- fused k_C: agg -> hid -> upd+res+LN -> (out | next P,Q) -----
// 256 threads = 4 waves; wave w owns cols [16w,16w+16); lane = node-in-block.
template<int LAST>
__global__ void __launch_bounds__(256) k_C(
    float* __restrict__ PS, float* __restrict__ h, float* __restrict__ Qb,
    const float4* __restrict__ nf, const float* __restrict__ wf, int l,
    void* __restrict__ dout, long obase, const int* __restrict__ flag)
{
  __shared__ float  xs[64][65];
  __shared__ float2 part[4][64];
  int lane = threadIdx.x & 63;
  int wv = threadIdx.x >> 6;
  int cb = __builtin_amdgcn_readfirstlane(wv * 16);
  int node = blockIdx.x*64 + lane;

  // ---- P0: agg = S@W2 + sg*b2 ----
  float acc[16], acc2[16];
  float sgi = nf[node].w;
  #pragma unroll
  for (int c=0;c<16;c++) acc[c] = sgi * wf[MB2 + l*64 + cb + c];
  const float* Srow = PS + (size_t)node*64;
  const float* w2l = wf + MW2 + l*4096;
  #pragma unroll 4
  for (int j=0;j<64;j++){
    float xj = Srow[j];
    const float* wr = w2l + j*64 + cb;
    #pragma unroll
    for (int c=0;c<16;c++) acc[c] = fmaf(xj, wr[c], acc[c]);
  }
  #pragma unroll
  for (int c=0;c<16;c++) xs[lane][cb+c] = acc[c];
  __syncthreads();

  // ---- P1: hid = gelu(h@U1a + agg@U1b + b1) ----
  #pragma unroll
  for (int c=0;c<16;c++) acc2[c] = wf[UB1 + l*64 + cb + c];
  const float* hrow = h + (size_t)node*64;
  const float* u1l = wf + UW1 + l*8192;
  #pragma unroll 2
  for (int j=0;j<64;j++){
    float hj = hrow[j];
    float aj = xs[lane][j];
    const float* wra = u1l + j*64 + cb;
    const float* wrb = u1l + (64+j)*64 + cb;
    #pragma unroll
    for (int c=0;c<16;c++) acc2[c] = fmaf(hj, wra[c], fmaf(aj, wrb[c], acc2[c]));
  }
  #pragma unroll
  for (int c=0;c<16;c++) acc2[c] = gelu_t(acc2[c]);
  __syncthreads();
  #pragma unroll
  for (int c=0;c<16;c++) xs[lane][cb+c] = acc2[c];
  __syncthreads();

  // ---- P2: upd = hid@U2 + b2; residual; LN ----
  const float* u2l = wf + UW2 + l*4096;
  #pragma unroll
  for (int c=0;c<16;c++) acc[c] = wf[UB2 + l*64 + cb + c];
  #pragma unroll 4
  for (int j=0;j<64;j++){
    float xj = xs[lane][j];
    const float* wr = u2l + j*64 + cb;
    #pragma unroll
    for (int c=0;c<16;c++) acc[c] = fmaf(xj, wr[c], acc[c]);
  }
  #pragma unroll
  for (int q=0;q<4;q++){
    float4 v = *(const float4*)(hrow + cb + 4*q);
    acc[4*q+0] += v.x; acc[4*q+1] += v.y; acc[4*q+2] += v.z; acc[4*q+3] += v.w;
  }
  float s1 = 0.f, s2 = 0.f;
  #pragma unroll
  for (int c=0;c<16;c++){ s1 += acc[c]; s2 = fmaf(acc[c], acc[c], s2); }
  part[wv][lane] = make_float2(s1, s2);
  __syncthreads();
  float m = 0.f, v2 = 0.f;
  #pragma unroll
  for (int ww=0; ww<4; ww++){ float2 pp = part[ww][lane]; m += pp.x; v2 += pp.y; }
  m *= (1.0f/64.0f);
  v2 = v2*(1.0f/64.0f) - m*m;
  float inv = frsq(v2 + 1e-5f);
  float hp[16];
  #pragma unroll
  for (int c=0;c<16;c++)
    hp[c] = (acc[c]-m)*inv*wf[LNG + l*64 + cb + c] + wf[LNB + l*64 + cb + c];

  if (LAST){
    float po = 0.f;
    #pragma unroll
    for (int c=0;c<16;c++) po = fmaf(hp[c], wf[OUTW + cb + c], po);
    __syncthreads();
    part[wv][lane].x = po;
    __syncthreads();
    if (wv == 0){
      float o = wf[OUTB] + part[0][lane].x + part[1][lane].x + part[2][lane].x + part[3][lane].x;
      stf(dout, obase + node, o, *flag);
    }
  } else {
    float* hw = h + (size_t)node*64 + cb;
    #pragma unroll
    for (int q=0;q<4;q++)
      *(float4*)(hw + 4*q) = make_float4(hp[4*q],hp[4*q+1],hp[4*q+2],hp[4*q+3]);
    __syncthreads();                 // all P2 reads of xs done
    #pragma unroll
    for (int c=0;c<16;c++) xs[lane][cb+c] = hp[c];
    __syncthreads();
    // ---- P3: P' = h'@W1a(l+1), Q' = h'@W1b(l+1) ----
    const float* w1n = wf + MW1 + (l+1)*8320;
    #pragma unroll
    for (int c=0;c<16;c++){ acc[c] = 0.f; acc2[c] = 0.f; }
    #pragma unroll 2
    for (int j=0;j<64;j++){
      float xj = xs[lane][j];
      const float* wp = w1n + j*64 + cb;
      const float* wq = w1n + (64+j)*64 + cb;
      #pragma unroll
      for (int c=0;c<16;c++){
        acc[c]  = fmaf(xj, wp[c], acc[c]);
        acc2[c] = fmaf(xj, wq[c], acc2[c]);
      }
    }
    float* prow = PS + (size_t)node*64 + cb;
    float* qrow = Qb + (size_t)node*64 + cb;
    #pragma unroll
    for (int q=0;q<4;q++){
      *(float4*)(prow + 4*q) = make_float4(acc[4*q],acc[4*q+1],acc[4*q+2],acc[4*q+3]);
      *(float4*)(qrow + 4*q) = make_float4(acc2[4*q],acc2[4*q+1],acc2[4*q+2],acc2[4*q+3]);
    }
  }
}

// ---------------- host launcher ----------------
extern "C" void kernel_launch(void* const* d_in, const int* in_sizes, int n_in,
                              void* d_out, int out_size, void* d_ws, size_t ws_size,
                              hipStream_t stream)
{
  if (ws_size < (size_t)WS_NEED_FLOATS * 4ull) {
    k_encode<<<(OUTTOT+255)/256, 256, 0, stream>>>((bf16*)d_out, (float)ws_size);
    return;
  }

  float* ws   = (float*)d_ws;
  float* h    = ws + H_OFF;
  float* PS   = ws + PS_OFF;
  float* Qb   = ws + Q_OFF;
  float* nfw  = ws + NF_OFF;
  float4* nf  = (float4*)nfw;
  float* wf   = ws + WF_OFF;
  int*  flag  = (int*)(ws + FLAG_OFF);

  k_sniff<<<1, 64, 0, stream>>>(d_in[1], flag);

  WArgs wa;
  static const int cnts[18] = {64,64,24960,192,12288,192,1344,192,192,3,24576,192,12288,192,192,192,64,1};
  static const int offs[18] = {IN_W,IN_B,MW1,MB1,MW2,MB2,GW1,GB1,GW2,GB2,UW1,UB1,UW2,UB2,LNG,LNB,OUTW,OUTB};
  for (int k = 0; k < 18; k++){ wa.p[k] = d_in[4+k]; wa.cnt[k] = cnts[k]; wa.off[k] = offs[k]; }
  k_conv<<<dim3(98,18), 256, 0, stream>>>(wa, wf, flag);

  for (int b = 0; b < NB; b++){
    k_feat<<<256, 256, 0, stream>>>(d_in[1], (long)b*NPN, flag, nf);
    k_init<<<1024, 256, 0, stream>>>(nf, h, PS, Qb, wf);

    for (int l = 0; l < 3; l++){
      k_B<<<16384, 256, 0, stream>>>(PS, Qb, nf, nfw, wf, l,
          d_out, (long)NNODES + (long)l*NE + (long)b*EPB, flag);
      if (l < 2)
        k_C<0><<<1024, 256, 0, stream>>>(PS, h, Qb, nf, wf, l, d_out, (long)b*NPN, flag);
      else
        k_C<1><<<1024, 256, 0, stream>>>(PS, h, Qb, nf, wf, l, d_out, (long)b*NPN, flag);
    }
  }
}

// Round 6
// 630.704 us; speedup vs baseline: 2.3793x; 1.1053x over previous
//
#include <hip/hip_runtime.h>
#include <hip/hip_bf16.h>

// ---------------- problem constants ----------------
#define NTT 128
#define NXX 512
#define NB  2
#define NPN (NTT*NXX)        // 65536 nodes per batch
#define NNODES (NB*NPN)      // 131072
#define EPB 520452           // edges per batch
#define NE  (NB*EPB)         // 1040904 total edges
#define OUTTOT (NNODES + 3*NE)   // 3253784

// ---------------- workspace layout (float offsets) ----------------
#define H_OFF    0u
#define PS_OFF   4194304u
#define Q_OFF    8388608u
#define NF_OFF   12582912u   // float4 per node: (u, dux, dut, sg)
#define WF_OFF   12845056u
#define FLAG_OFF 12922248u
#define WS_NEED_FLOATS 12922252u   // identical to round-4/5 proven-OK footprint

// f32 weight sub-offsets inside wf
#define IN_W 0
#define IN_B 64
#define MW1  128      // (3,130,64) per-layer stride 8320
#define MB1  25088    // (3,64)
#define MW2  25280    // (3,64,64) stride 4096
#define MB2  37568
#define GW1  37760    // (3,7,64) stride 448
#define GB1  39104
#define GW2  39296    // (3,64)
#define GB2  39488    // (3)
#define UW1  39492    // (3,128,64) stride 8192
#define UB1  64068
#define UW2  64260    // (3,64,64) stride 4096
#define UB2  76548
#define LNG  76740
#define LNB  76932
#define OUTW 77124
#define OUTB 77188

typedef __hip_bfloat16 bf16;

__device__ __forceinline__ float b2f(bf16 x){ return __bfloat162float(x); }

__device__ __forceinline__ float fexp2(float x){
#if __has_builtin(__builtin_amdgcn_exp2f)
  return __builtin_amdgcn_exp2f(x);
#else
  return exp2f(x);
#endif
}
__device__ __forceinline__ float frcp(float x){
#if __has_builtin(__builtin_amdgcn_rcpf)
  return __builtin_amdgcn_rcpf(x);
#else
  return 1.0f/x;
#endif
}
__device__ __forceinline__ float frsq(float x){
#if __has_builtin(__builtin_amdgcn_rsqf)
  return __builtin_amdgcn_rsqf(x);
#else
  return rsqrtf(x);
#endif
}
// tanh-approx GELU, exp2-folded
__device__ __forceinline__ float gelu_t(float v){
  float vv = v*v;
  float w  = v*fmaf(vv, 0.1029445f, 2.3022080f);
  float r  = frcp(1.0f + fexp2(w));
  return fmaf(-v, r, v);
}
__device__ __forceinline__ float sigm(float x){
  return frcp(1.0f + fexp2(-1.44269504f*x));
}
// dtype-agnostic input load / output store (isf: 1 = float32, 0 = bf16)
__device__ __forceinline__ float ldf(const void* p, long i, int isf){
  return isf ? ((const float*)p)[i] : b2f(((const bf16*)p)[i]);
}
__device__ __forceinline__ void stf(void* p, long i, float v, int isf){
  if (isf) ((float*)p)[i] = v;
  else ((bf16*)p)[i] = __float2bfloat16(v);
}

// ---------------- dtype sniff ----------------
__global__ void k_sniff(const void* __restrict__ u, int* __restrict__ flag)
{
  int tid = threadIdx.x;
  unsigned w = ((const unsigned*)u)[tid];
  int bad = 0;
  #pragma unroll
  for (int h=0; h<2; h++){
    unsigned bits = ((h ? (w>>16) : (w & 0xffffu)) << 16);
    float v = __uint_as_float(bits);
    if (!(v == v) || fabsf(v) > 64.0f) bad = 1;
  }
  unsigned long long anybad = __ballot(bad);
  if (tid == 0) *flag = (anybad != 0ull) ? 1 : 0;
}

// ---------------- diagnostic fallback ----------------
__global__ void __launch_bounds__(256) k_encode(bf16* __restrict__ out, float val)
{
  int i = blockIdx.x*256 + threadIdx.x;
  if (i < OUTTOT) out[i] = __float2bfloat16(i == 0 ? val : 0.0f);
}

// ---------------- convert all weights to f32 scratch ----------------
struct WArgs { const void* p[18]; int cnt[18]; int off[18]; };

__global__ void __launch_bounds__(256) k_conv(WArgs a, float* __restrict__ wf,
                                              const int* __restrict__ flag)
{
  int y = blockIdx.y;
  int i = blockIdx.x*256 + threadIdx.x;
  int isf = *flag;
  if (i < a.cnt[y]) wf[a.off[y] + i] = ldf(a.p[y], i, isf);
}

// ---------------- node features: nf = (u, du/dx, du/dt, 0) ----------------
__global__ void __launch_bounds__(256) k_feat(
    const void* __restrict__ ub, long ubase, const int* __restrict__ flag,
    float4* __restrict__ nf)
{
  int i = blockIdx.x*256 + threadIdx.x;   // [0, NPN)
  int isf = *flag;
  int t = i >> 9, n = i & 511;
  float uc = ldf(ub, ubase + i, isf);
  float dxv;
  if (n == 0)          dxv = (ldf(ub, ubase + t*NXX + 1, isf) - uc) * 512.0f;
  else if (n == NXX-1) dxv = (uc - ldf(ub, ubase + t*NXX + NXX-2, isf)) * 512.0f;
  else                 dxv = (ldf(ub, ubase + t*NXX + n+1, isf) - ldf(ub, ubase + t*NXX + n-1, isf)) * 256.0f;
  float dtv;
  if (t == 0)          dtv = (ldf(ub, ubase + NXX + n, isf) - uc) * 128.0f;
  else if (t == NTT-1) dtv = (uc - ldf(ub, ubase + (NTT-2)*NXX + n, isf)) * 128.0f;
  else                 dtv = (ldf(ub, ubase + (t+1)*NXX + n, isf) - ldf(ub, ubase + (t-1)*NXX + n, isf)) * 64.0f;
  nf[i] = make_float4(uc, dxv, dtv, 0.0f);
}

// ---------------- k_init: h0 = u*in_w+in_b; P=h0@W1a, Q=h0@W1b (layer 0) ------
__global__ void __launch_bounds__(256) k_init(
    const float4* __restrict__ nf, float* __restrict__ h,
    float* __restrict__ PS, float* __restrict__ Qb, const float* __restrict__ wf)
{
  int lane = threadIdx.x & 63;
  int cb = __builtin_amdgcn_readfirstlane((threadIdx.x >> 6) * 16);
  int node = blockIdx.x*64 + lane;
  float ui = nf[node].x;
  const float* w1 = wf + MW1;   // layer 0
  float accP[16], accQ[16];
  #pragma unroll
  for (int c=0;c<16;c++){ accP[c]=0.f; accQ[c]=0.f; }
  #pragma unroll 2
  for (int j=0;j<64;j++){
    float h0j = fmaf(ui, wf[IN_W+j], wf[IN_B+j]);
    const float* wp = w1 + j*64 + cb;
    const float* wq = w1 + (64+j)*64 + cb;
    #pragma unroll
    for (int c=0;c<16;c++){
      accP[c] = fmaf(h0j, wp[c], accP[c]);
      accQ[c] = fmaf(h0j, wq[c], accQ[c]);
    }
  }
  float* hrow = h + (size_t)node*64 + cb;
  float* prow = PS + (size_t)node*64 + cb;
  float* qrow = Qb + (size_t)node*64 + cb;
  #pragma unroll
  for (int q=0;q<4;q++){
    float4 hv;
    hv.x = fmaf(ui, wf[IN_W+cb+4*q+0], wf[IN_B+cb+4*q+0]);
    hv.y = fmaf(ui, wf[IN_W+cb+4*q+1], wf[IN_B+cb+4*q+1]);
    hv.z = fmaf(ui, wf[IN_W+cb+4*q+2], wf[IN_B+cb+4*q+2]);
    hv.w = fmaf(ui, wf[IN_W+cb+4*q+3], wf[IN_B+cb+4*q+3]);
    *(float4*)(hrow + 4*q) = hv;
    *(float4*)(prow + 4*q) = make_float4(accP[4*q],accP[4*q+1],accP[4*q+2],accP[4*q+3]);
    *(float4*)(qrow + 4*q) = make_float4(accQ[4*q],accQ[4*q+1],accQ[4*q+2],accQ[4*q+3]);
  }
}

// ---------------- phase B v2: edges (wave per dst node, lane = channel) -------
// Single merged k-loop; scalar-uniform bounds branches; saddr Q loads;
// one sigmoid per lane + shfl-broadcast gates; single store branch.
__global__ void __launch_bounds__(256) k_B(
    float* __restrict__ PS, const float* __restrict__ Qb,
    const float4* __restrict__ nf, float* __restrict__ nfw,
    const float* __restrict__ wf, int l,
    void* __restrict__ dout, long gbase, const int* __restrict__ flag)
{
  // edge k: src j = iu + DELTA[k]
  constexpr int DELTA[8] = {512,-512,1,-1,513,511,-511,-513};
  constexpr int BASEa[8] = {0,65024,130048,195456,260864,325761,390658,455555};
  constexpr int TLOa[8]  = {1,0,0,0,1,1,0,0};
  constexpr int NLOa[8]  = {0,0,1,0,1,0,1,0};
  constexpr int NCNa[8]  = {512,512,511,511,511,511,511,511};
  constexpr int DTKa[8]  = {-1,1,0,0,-1,-1,1,1};
  constexpr int DNKa[8]  = {0,0,-1,1,-1,1,-1,1};

  int lane = threadIdx.x & 63;
  int iu = __builtin_amdgcn_readfirstlane(blockIdx.x*4 + (threadIdx.x >> 6));
  int isf = *flag;
  int tu = iu >> 9, nu = iu & 511;

  const float* gw1 = wf + GW1 + l*448;
  float Pi = PS[(size_t)iu*64 + lane];
  float4 fi = nf[iu];
  float g1 = gw1[64+lane], g2 = gw1[128+lane];
  float g4 = gw1[256+lane], g6 = gw1[384+lane];
  float a_i = wf[GB1 + l*64 + lane];
  a_i = fmaf(fi.x, gw1[lane],     a_i);
  a_i = fmaf(fi.y, gw1[192+lane], a_i);
  a_i = fmaf(fi.z, gw1[320+lane], a_i);
  float gw2v = wf[GW2 + l*64 + lane];
  float gb2v = wf[GB2 + l];
  const float* w1l = wf + MW1 + l*8320;
  float ecA = w1l[128*64+lane] * (1.0f/512.0f);
  float ecB = w1l[129*64+lane] * (1.0f/128.0f);
  float baseP = Pi + wf[MB1 + l*64 + lane];

  // per-edge message-pre bases: baseP + sx*ecA + st*ecB
  float bp[8];
  bp[0] = baseP - ecB;        bp[1] = baseP + ecB;
  bp[2] = baseP - ecA;        bp[3] = baseP + ecA;
  bp[4] = baseP - ecA - ecB;  bp[5] = baseP + ecA - ecB;
  bp[6] = baseP - ecA + ecB;  bp[7] = baseP + ecA + ecB;

  // node-uniform validity
  bool vT0 = (tu >= 1), vT1 = (tu <= NTT-2);
  bool vN0 = (nu >= 1), vN1 = (nu <= NXX-2);
  bool val[8] = { vT1, vT0, vN1, vN0, vT1&&vN1, vT1&&vN0, vT0&&vN1, vT0&&vN0 };

  int vidx = iu*64 + lane;   // shared v-index for all Q loads

  float gg[8], m[8];
  #pragma unroll
  for (int k=0;k<8;k++){ gg[k] = 0.f; m[k] = 0.f; }

  #pragma unroll
  for (int k=0;k<8;k++){
    if (val[k]){                                   // scalar, node-uniform branch
      const float* Qk = Qb + DELTA[k]*64;          // uniform base (SGPR)
      float  Qj = Qk[vidx];
      float4 fj = nf[iu + DELTA[k]];               // uniform (scalar load)
      float hg = fmaf(fj.x, g1, a_i);
      hg = fmaf(fj.y, g4, hg);
      hg = fmaf(fj.z, g6, hg);
      hg = fmaf(fabsf(fi.x - fj.x), g2, hg);       // |..| is scalar
      gg[k] = gelu_t(hg) * gw2v;
      m[k]  = gelu_t(Qj + bp[k]);
    }
  }

  // butterfly reduce all 8 gate sums across 64 lanes
  #pragma unroll
  for (int o=32;o;o>>=1){
    #pragma unroll
    for (int k=0;k<8;k++) gg[k] += __shfl_xor(gg[k], o);
  }
  // one sigmoid per lane on the lane&7-selected sum, then broadcast
  float s01 = (lane&1) ? gg[1] : gg[0];
  float s23 = (lane&1) ? gg[3] : gg[2];
  float s45 = (lane&1) ? gg[5] : gg[4];
  float s67 = (lane&1) ? gg[7] : gg[6];
  float s03 = (lane&2) ? s23 : s01;
  float s47 = (lane&2) ? s67 : s45;
  float sel = (lane&4) ? s47 : s03;
  float sg  = sigm(sel + gb2v);
  float gk[8];
  #pragma unroll
  for (int k=0;k<8;k++) gk[k] = __shfl(sg, k);

  float Sacc = 0.f, sga = 0.f;
  #pragma unroll
  for (int k=0;k<8;k++){
    if (val[k]){
      Sacc = fmaf(gk[k], m[k], Sacc);
      sga += gk[k];
    }
  }

  PS[(size_t)iu*64 + lane] = Sacc;

  if (lane == 0){
    #pragma unroll
    for (int k=0;k<8;k++){
      if (val[k]){
        int ts = tu - DTKa[k], ns = nu - DNKa[k];
        long eid = gbase + BASEa[k] + (ts - TLOa[k])*NCNa[k] + (ns - NLOa[k]);
        stf(dout, eid, gk[k], isf);
      }
    }
    nfw[4*iu + 3] = sga;
  }
}

// ---------------- fused k_C: agg -> hid -> upd+res+LN -> (out | next P,Q) -----
template<int LAST>
__global__ void __launch_bounds__(256) k_C(
    float* __restrict__ PS, float* __restrict__ h, float* __restrict__ Qb,
    const float4* __restrict__ nf, const float* __restrict__ wf, int l,
    void* __restrict__ dout, long obase, const int* __restrict__ flag)
{
  __shared__ float  xs[64][65];
  __shared__ float2 part[4][64];
  int lane = threadIdx.x & 63;
  int wv = threadIdx.x >> 6;
  int cb = __builtin_amdgcn_readfirstlane(wv * 16);
  int node = blockIdx.x*64 + lane;

  // ---- P0: agg = S@W2 + sg*b2 ----
  float acc[16], acc2[16];
  float sgi = nf[node].w;
  #pragma unroll
  for (int c=0;c<16;c++) acc[c] = sgi * wf[MB2 + l*64 + cb + c];
  const float* Srow = PS + (size_t)node*64;
  const float* w2l = wf + MW2 + l*4096;
  #pragma unroll 4
  for (int j=0;j<64;j++){
    float xj = Srow[j];
    const float* wr = w2l + j*64 + cb;
    #pragma unroll
    for (int c=0;c<16;c++) acc[c] = fmaf(xj, wr[c], acc[c]);
  }
  #pragma unroll
  for (int c=0;c<16;c++) xs[lane][cb+c] = acc[c];
  __syncthreads();

  // ---- P1: hid = gelu(h@U1a + agg@U1b + b1) ----
  #pragma unroll
  for (int c=0;c<16;c++) acc2[c] = wf[UB1 + l*64 + cb + c];
  const float* hrow = h + (size_t)node*64;
  const float* u1l = wf + UW1 + l*8192;
  #pragma unroll 2
  for (int j=0;j<64;j++){
    float hj = hrow[j];
    float aj = xs[lane][j];
    const float* wra = u1l + j*64 + cb;
    const float* wrb = u1l + (64+j)*64 + cb;
    #pragma unroll
    for (int c=0;c<16;c++) acc2[c] = fmaf(hj, wra[c], fmaf(aj, wrb[c], acc2[c]));
  }
  #pragma unroll
  for (int c=0;c<16;c++) acc2[c] = gelu_t(acc2[c]);
  __syncthreads();
  #pragma unroll
  for (int c=0;c<16;c++) xs[lane][cb+c] = acc2[c];
  __syncthreads();

  // ---- P2: upd = hid@U2 + b2; residual; LN ----
  const float* u2l = wf + UW2 + l*4096;
  #pragma unroll
  for (int c=0;c<16;c++) acc[c] = wf[UB2 + l*64 + cb + c];
  #pragma unroll 4
  for (int j=0;j<64;j++){
    float xj = xs[lane][j];
    const float* wr = u2l + j*64 + cb;
    #pragma unroll
    for (int c=0;c<16;c++) acc[c] = fmaf(xj, wr[c], acc[c]);
  }
  #pragma unroll
  for (int q=0;q<4;q++){
    float4 v = *(const float4*)(hrow + cb + 4*q);
    acc[4*q+0] += v.x; acc[4*q+1] += v.y; acc[4*q+2] += v.z; acc[4*q+3] += v.w;
  }
  float s1 = 0.f, s2 = 0.f;
  #pragma unroll
  for (int c=0;c<16;c++){ s1 += acc[c]; s2 = fmaf(acc[c], acc[c], s2); }
  part[wv][lane] = make_float2(s1, s2);
  __syncthreads();
  float m = 0.f, v2 = 0.f;
  #pragma unroll
  for (int ww=0; ww<4; ww++){ float2 pp = part[ww][lane]; m += pp.x; v2 += pp.y; }
  m *= (1.0f/64.0f);
  v2 = v2*(1.0f/64.0f) - m*m;
  float inv = frsq(v2 + 1e-5f);
  float hp[16];
  #pragma unroll
  for (int c=0;c<16;c++)
    hp[c] = (acc[c]-m)*inv*wf[LNG + l*64 + cb + c] + wf[LNB + l*64 + cb + c];

  if (LAST){
    float po = 0.f;
    #pragma unroll
    for (int c=0;c<16;c++) po = fmaf(hp[c], wf[OUTW + cb + c], po);
    __syncthreads();
    part[wv][lane].x = po;
    __syncthreads();
    if (wv == 0){
      float o = wf[OUTB] + part[0][lane].x + part[1][lane].x + part[2][lane].x + part[3][lane].x;
      stf(dout, obase + node, o, *flag);
    }
  } else {
    float* hw = h + (size_t)node*64 + cb;
    #pragma unroll
    for (int q=0;q<4;q++)
      *(float4*)(hw + 4*q) = make_float4(hp[4*q],hp[4*q+1],hp[4*q+2],hp[4*q+3]);
    __syncthreads();
    #pragma unroll
    for (int c=0;c<16;c++) xs[lane][cb+c] = hp[c];
    __syncthreads();
    // ---- P3: P' = h'@W1a(l+1), Q' = h'@W1b(l+1) ----
    const float* w1n = wf + MW1 + (l+1)*8320;
    #pragma unroll
    for (int c=0;c<16;c++){ acc[c] = 0.f; acc2[c] = 0.f; }
    #pragma unroll 2
    for (int j=0;j<64;j++){
      float xj = xs[lane][j];
      const float* wp = w1n + j*64 + cb;
      const float* wq = w1n + (64+j)*64 + cb;
      #pragma unroll
      for (int c=0;c<16;c++){
        acc[c]  = fmaf(xj, wp[c], acc[c]);
        acc2[c] = fmaf(xj, wq[c], acc2[c]);
      }
    }
    float* prow = PS + (size_t)node*64 + cb;
    float* qrow = Qb + (size_t)node*64 + cb;
    #pragma unroll
    for (int q=0;q<4;q++){
      *(float4*)(prow + 4*q) = make_float4(acc[4*q],acc[4*q+1],acc[4*q+2],acc[4*q+3]);
      *(float4*)(qrow + 4*q) = make_float4(acc2[4*q],acc2[4*q+1],acc2[4*q+2],acc2[4*q+3]);
    }
  }
}

// ---------------- host launcher ----------------
extern "C" void kernel_launch(void* const* d_in, const int* in_sizes, int n_in,
                              void* d_out, int out_size, void* d_ws, size_t ws_size,
                              hipStream_t stream)
{
  if (ws_size < (size_t)WS_NEED_FLOATS * 4ull) {
    k_encode<<<(OUTTOT+255)/256, 256, 0, stream>>>((bf16*)d_out, (float)ws_size);
    return;
  }

  float* ws   = (float*)d_ws;
  float* h    = ws + H_OFF;
  float* PS   = ws + PS_OFF;
  float* Qb   = ws + Q_OFF;
  float* nfw  = ws + NF_OFF;
  float4* nf  = (float4*)nfw;
  float* wf   = ws + WF_OFF;
  int*  flag  = (int*)(ws + FLAG_OFF);

  k_sniff<<<1, 64, 0, stream>>>(d_in[1], flag);

  WArgs wa;
  static const int cnts[18] = {64,64,24960,192,12288,192,1344,192,192,3,24576,192,12288,192,192,192,64,1};
  static const int offs[18] = {IN_W,IN_B,MW1,MB1,MW2,MB2,GW1,GB1,GW2,GB2,UW1,UB1,UW2,UB2,LNG,LNB,OUTW,OUTB};
  for (int k = 0; k < 18; k++){ wa.p[k] = d_in[4+k]; wa.cnt[k] = cnts[k]; wa.off[k] = offs[k]; }
  k_conv<<<dim3(98,18), 256, 0, stream>>>(wa, wf, flag);

  for (int b = 0; b < NB; b++){
    k_feat<<<256, 256, 0, stream>>>(d_in[1], (long)b*NPN, flag, nf);
    k_init<<<1024, 256, 0, stream>>>(nf, h, PS, Qb, wf);

    for (int l = 0; l < 3; l++){
      k_B<<<16384, 256, 0, stream>>>(PS, Qb, nf, nfw, wf, l,
          d_out, (long)NNODES + (long)l*NE + (long)b*EPB, flag);
      if (l < 2)
        k_C<0><<<1024, 256, 0, stream>>>(PS, h, Qb, nf, wf, l, d_out, (long)b*NPN, flag);
      else
        k_C<1><<<1024, 256, 0, stream>>>(PS, h, Qb, nf, wf, l, d_out, (long)b*NPN, flag);
    }
  }
}

// Round 7
// 615.001 us; speedup vs baseline: 2.4400x; 1.0255x over previous
//
#include <hip/hip_runtime.h>
#include <hip/hip_bf16.h>

// ---------------- problem constants ----------------
#define NTT 128
#define NXX 512
#define NB  2
#define NPN (NTT*NXX)        // 65536 nodes per batch
#define NNODES (NB*NPN)      // 131072
#define EPB 520452           // edges per batch
#define NE  (NB*EPB)         // 1040904 total edges
#define OUTTOT (NNODES + 3*NE)   // 3253784

// ---------------- workspace layout (float offsets) ----------------
#define H_OFF    0u
#define PS_OFF   4194304u
#define Q_OFF    8388608u
#define NF_OFF   12582912u   // float4 per node: (u, dux, dut, sg)
#define WF_OFF   12845056u
#define FLAG_OFF 12922248u
#define WS_NEED_FLOATS 12922252u   // proven-OK footprint

// f32 weight sub-offsets inside wf
#define IN_W 0
#define IN_B 64
#define MW1  128      // (3,130,64) per-layer stride 8320
#define MB1  25088    // (3,64)
#define MW2  25280    // (3,64,64) stride 4096
#define MB2  37568
#define GW1  37760    // (3,7,64) stride 448
#define GB1  39104
#define GW2  39296    // (3,64)
#define GB2  39488    // (3)
#define UW1  39492    // (3,128,64) stride 8192
#define UB1  64068
#define UW2  64260    // (3,64,64) stride 4096
#define UB2  76548
#define LNG  76740
#define LNB  76932
#define OUTW 77124
#define OUTB 77188

typedef __hip_bfloat16 bf16;

__device__ __forceinline__ float b2f(bf16 x){ return __bfloat162float(x); }

__device__ __forceinline__ float fexp2(float x){
#if __has_builtin(__builtin_amdgcn_exp2f)
  return __builtin_amdgcn_exp2f(x);
#else
  return exp2f(x);
#endif
}
__device__ __forceinline__ float frcp(float x){
#if __has_builtin(__builtin_amdgcn_rcpf)
  return __builtin_amdgcn_rcpf(x);
#else
  return 1.0f/x;
#endif
}
__device__ __forceinline__ float frsq(float x){
#if __has_builtin(__builtin_amdgcn_rsqf)
  return __builtin_amdgcn_rsqf(x);
#else
  return rsqrtf(x);
#endif
}
// tanh-approx GELU, exp2-folded
__device__ __forceinline__ float gelu_t(float v){
  float vv = v*v;
  float w  = v*fmaf(vv, 0.1029445f, 2.3022080f);
  float r  = frcp(1.0f + fexp2(w));
  return fmaf(-v, r, v);
}
__device__ __forceinline__ float sigm(float x){
  return frcp(1.0f + fexp2(-1.44269504f*x));
}
// dtype-agnostic input load / output store (isf: 1 = float32, 0 = bf16)
__device__ __forceinline__ float ldf(const void* p, long i, int isf){
  return isf ? ((const float*)p)[i] : b2f(((const bf16*)p)[i]);
}
__device__ __forceinline__ void stf(void* p, long i, float v, int isf){
  if (isf) ((float*)p)[i] = v;
  else ((bf16*)p)[i] = __float2bfloat16(v);
}

// ---------------- dtype sniff ----------------
__global__ void k_sniff(const void* __restrict__ u, int* __restrict__ flag)
{
  int tid = threadIdx.x;
  unsigned w = ((const unsigned*)u)[tid];
  int bad = 0;
  #pragma unroll
  for (int h=0; h<2; h++){
    unsigned bits = ((h ? (w>>16) : (w & 0xffffu)) << 16);
    float v = __uint_as_float(bits);
    if (!(v == v) || fabsf(v) > 64.0f) bad = 1;
  }
  unsigned long long anybad = __ballot(bad);
  if (tid == 0) *flag = (anybad != 0ull) ? 1 : 0;
}

// ---------------- diagnostic fallback ----------------
__global__ void __launch_bounds__(256) k_encode(bf16* __restrict__ out, float val)
{
  int i = blockIdx.x*256 + threadIdx.x;
  if (i < OUTTOT) out[i] = __float2bfloat16(i == 0 ? val : 0.0f);
}

// ---------------- convert all weights to f32 scratch ----------------
struct WArgs { const void* p[18]; int cnt[18]; int off[18]; };

__global__ void __launch_bounds__(256) k_conv(WArgs a, float* __restrict__ wf,
                                              const int* __restrict__ flag)
{
  int y = blockIdx.y;
  int i = blockIdx.x*256 + threadIdx.x;
  int isf = *flag;
  if (i < a.cnt[y]) wf[a.off[y] + i] = ldf(a.p[y], i, isf);
}

// ---------------- node features: nf = (u, du/dx, du/dt, 0) ----------------
__global__ void __launch_bounds__(256) k_feat(
    const void* __restrict__ ub, long ubase, const int* __restrict__ flag,
    float4* __restrict__ nf)
{
  int i = blockIdx.x*256 + threadIdx.x;   // [0, NPN)
  int isf = *flag;
  int t = i >> 9, n = i & 511;
  float uc = ldf(ub, ubase + i, isf);
  float dxv;
  if (n == 0)          dxv = (ldf(ub, ubase + t*NXX + 1, isf) - uc) * 512.0f;
  else if (n == NXX-1) dxv = (uc - ldf(ub, ubase + t*NXX + NXX-2, isf)) * 512.0f;
  else                 dxv = (ldf(ub, ubase + t*NXX + n+1, isf) - ldf(ub, ubase + t*NXX + n-1, isf)) * 256.0f;
  float dtv;
  if (t == 0)          dtv = (ldf(ub, ubase + NXX + n, isf) - uc) * 128.0f;
  else if (t == NTT-1) dtv = (uc - ldf(ub, ubase + (NTT-2)*NXX + n, isf)) * 128.0f;
  else                 dtv = (ldf(ub, ubase + (t+1)*NXX + n, isf) - ldf(ub, ubase + (t-1)*NXX + n, isf)) * 64.0f;
  nf[i] = make_float4(uc, dxv, dtv, 0.0f);
}

// ---------------- k_init: h0 = u*in_w+in_b; P=h0@W1a, Q=h0@W1b (layer 0) ------
__global__ void __launch_bounds__(256) k_init(
    const float4* __restrict__ nf, float* __restrict__ h,
    float* __restrict__ PS, float* __restrict__ Qb, const float* __restrict__ wf)
{
  int lane = threadIdx.x & 63;
  int cb = __builtin_amdgcn_readfirstlane((threadIdx.x >> 6) * 16);
  int node = blockIdx.x*64 + lane;
  float ui = nf[node].x;
  const float* w1 = wf + MW1;   // layer 0
  float accP[16], accQ[16];
  #pragma unroll
  for (int c=0;c<16;c++){ accP[c]=0.f; accQ[c]=0.f; }
  #pragma unroll 2
  for (int j=0;j<64;j++){
    float h0j = fmaf(ui, wf[IN_W+j], wf[IN_B+j]);
    const float* wp = w1 + j*64 + cb;
    const float* wq = w1 + (64+j)*64 + cb;
    #pragma unroll
    for (int c=0;c<16;c++){
      accP[c] = fmaf(h0j, wp[c], accP[c]);
      accQ[c] = fmaf(h0j, wq[c], accQ[c]);
    }
  }
  float* hrow = h + (size_t)node*64 + cb;
  float* prow = PS + (size_t)node*64 + cb;
  float* qrow = Qb + (size_t)node*64 + cb;
  #pragma unroll
  for (int q=0;q<4;q++){
    float4 hv;
    hv.x = fmaf(ui, wf[IN_W+cb+4*q+0], wf[IN_B+cb+4*q+0]);
    hv.y = fmaf(ui, wf[IN_W+cb+4*q+1], wf[IN_B+cb+4*q+1]);
    hv.z = fmaf(ui, wf[IN_W+cb+4*q+2], wf[IN_B+cb+4*q+2]);
    hv.w = fmaf(ui, wf[IN_W+cb+4*q+3], wf[IN_B+cb+4*q+3]);
    *(float4*)(hrow + 4*q) = hv;
    *(float4*)(prow + 4*q) = make_float4(accP[4*q],accP[4*q+1],accP[4*q+2],accP[4*q+3]);
    *(float4*)(qrow + 4*q) = make_float4(accQ[4*q],accQ[4*q+1],accQ[4*q+2],accQ[4*q+3]);
  }
}

// ---------------- phase B: edges (wave per dst node, lane = channel) ----------
__global__ void __launch_bounds__(256) k_B(
    float* __restrict__ PS, const float* __restrict__ Qb,
    const float4* __restrict__ nf, float* __restrict__ nfw,
    const float* __restrict__ wf, int l,
    void* __restrict__ dout, long gbase, const int* __restrict__ flag)
{
  constexpr int DELTA[8] = {512,-512,1,-1,513,511,-511,-513};
  constexpr int BASEa[8] = {0,65024,130048,195456,260864,325761,390658,455555};
  constexpr int TLOa[8]  = {1,0,0,0,1,1,0,0};
  constexpr int NLOa[8]  = {0,0,1,0,1,0,1,0};
  constexpr int NCNa[8]  = {512,512,511,511,511,511,511,511};
  constexpr int DTKa[8]  = {-1,1,0,0,-1,-1,1,1};
  constexpr int DNKa[8]  = {0,0,-1,1,-1,1,-1,1};

  int lane = threadIdx.x & 63;
  int iu = __builtin_amdgcn_readfirstlane(blockIdx.x*4 + (threadIdx.x >> 6));
  int isf = *flag;
  int tu = iu >> 9, nu = iu & 511;

  const float* gw1 = wf + GW1 + l*448;
  float Pi = PS[(size_t)iu*64 + lane];
  float4 fi = nf[iu];
  float g1 = gw1[64+lane], g2 = gw1[128+lane];
  float g4 = gw1[256+lane], g6 = gw1[384+lane];
  float a_i = wf[GB1 + l*64 + lane];
  a_i = fmaf(fi.x, gw1[lane],     a_i);
  a_i = fmaf(fi.y, gw1[192+lane], a_i);
  a_i = fmaf(fi.z, gw1[320+lane], a_i);
  float gw2v = wf[GW2 + l*64 + lane];
  float gb2v = wf[GB2 + l];
  const float* w1l = wf + MW1 + l*8320;
  float ecA = w1l[128*64+lane] * (1.0f/512.0f);
  float ecB = w1l[129*64+lane] * (1.0f/128.0f);
  float baseP = Pi + wf[MB1 + l*64 + lane];

  float bp[8];
  bp[0] = baseP - ecB;        bp[1] = baseP + ecB;
  bp[2] = baseP - ecA;        bp[3] = baseP + ecA;
  bp[4] = baseP - ecA - ecB;  bp[5] = baseP + ecA - ecB;
  bp[6] = baseP - ecA + ecB;  bp[7] = baseP + ecA + ecB;

  bool vT0 = (tu >= 1), vT1 = (tu <= NTT-2);
  bool vN0 = (nu >= 1), vN1 = (nu <= NXX-2);
  bool val[8] = { vT1, vT0, vN1, vN0, vT1&&vN1, vT1&&vN0, vT0&&vN1, vT0&&vN0 };

  int vidx = iu*64 + lane;

  float gg[8], m[8];
  #pragma unroll
  for (int k=0;k<8;k++){ gg[k] = 0.f; m[k] = 0.f; }

  #pragma unroll
  for (int k=0;k<8;k++){
    if (val[k]){
      const float* Qk = Qb + DELTA[k]*64;
      float  Qj = Qk[vidx];
      float4 fj = nf[iu + DELTA[k]];
      float hg = fmaf(fj.x, g1, a_i);
      hg = fmaf(fj.y, g4, hg);
      hg = fmaf(fj.z, g6, hg);
      hg = fmaf(fabsf(fi.x - fj.x), g2, hg);
      gg[k] = gelu_t(hg) * gw2v;
      m[k]  = gelu_t(Qj + bp[k]);
    }
  }

  #pragma unroll
  for (int o=32;o;o>>=1){
    #pragma unroll
    for (int k=0;k<8;k++) gg[k] += __shfl_xor(gg[k], o);
  }
  float s01 = (lane&1) ? gg[1] : gg[0];
  float s23 = (lane&1) ? gg[3] : gg[2];
  float s45 = (lane&1) ? gg[5] : gg[4];
  float s67 = (lane&1) ? gg[7] : gg[6];
  float s03 = (lane&2) ? s23 : s01;
  float s47 = (lane&2) ? s67 : s45;
  float sel = (lane&4) ? s47 : s03;
  float sg  = sigm(sel + gb2v);
  float gk[8];
  #pragma unroll
  for (int k=0;k<8;k++) gk[k] = __shfl(sg, k);

  float Sacc = 0.f, sga = 0.f;
  #pragma unroll
  for (int k=0;k<8;k++){
    if (val[k]){
      Sacc = fmaf(gk[k], m[k], Sacc);
      sga += gk[k];
    }
  }

  PS[(size_t)iu*64 + lane] = Sacc;

  if (lane == 0){
    #pragma unroll
    for (int k=0;k<8;k++){
      if (val[k]){
        int ts = tu - DTKa[k], ns = nu - DNKa[k];
        long eid = gbase + BASEa[k] + (ts - TLOa[k])*NCNa[k] + (ns - NLOa[k]);
        stf(dout, eid, gk[k], isf);
      }
    }
    nfw[4*iu + 3] = sga;
  }
}

// ---------------- fused k_C v2: LDS-staged tiles, agg->hid->upd+LN->(out|P,Q) -
// 256 threads = 4 waves; wave w owns cols [16w,16w+16); lane = node-in-block.
// S-tile and h-tile staged coalesced into LDS; all GEMM x-reads hit LDS.
template<int LAST>
__global__ void __launch_bounds__(256) k_C(
    float* __restrict__ PS, float* __restrict__ h, float* __restrict__ Qb,
    const float4* __restrict__ nf, const float* __restrict__ wf, int l,
    void* __restrict__ dout, long obase, const int* __restrict__ flag)
{
  __shared__ float  sh[64][65];   // S -> agg -> hid -> h'
  __shared__ float  hh[64][65];   // h (residual + P1 operand)
  __shared__ float2 part[4][64];
  int tid  = threadIdx.x;
  int lane = tid & 63;
  int wv = tid >> 6;
  int cb = __builtin_amdgcn_readfirstlane(wv * 16);
  int node = blockIdx.x*64 + lane;

  // ---- stage S-tile and h-tile (coalesced float4, conflict-free scatter) ----
  {
    const float4* Sg = (const float4*)(PS + (size_t)blockIdx.x*64*64);
    const float4* Hg = (const float4*)(h  + (size_t)blockIdx.x*64*64);
    #pragma unroll
    for (int p=0;p<4;p++){
      int f4 = tid + p*256;          // 0..1023
      int nd = f4 >> 4, q = (f4 & 15) << 2;
      float4 vs = Sg[f4];
      sh[nd][q+0]=vs.x; sh[nd][q+1]=vs.y; sh[nd][q+2]=vs.z; sh[nd][q+3]=vs.w;
      float4 vh = Hg[f4];
      hh[nd][q+0]=vh.x; hh[nd][q+1]=vh.y; hh[nd][q+2]=vh.z; hh[nd][q+3]=vh.w;
    }
  }
  __syncthreads();

  // ---- P0: agg = S@W2 + sg*b2 ----
  float acc[16], acc2[16];
  float sgi = nf[node].w;
  #pragma unroll
  for (int c=0;c<16;c++) acc[c] = sgi * wf[MB2 + l*64 + cb + c];
  const float* w2l = wf + MW2 + l*4096;
  #pragma unroll 4
  for (int j=0;j<64;j++){
    float xj = sh[lane][j];
    const float* wr = w2l + j*64 + cb;
    #pragma unroll
    for (int c=0;c<16;c++) acc[c] = fmaf(xj, wr[c], acc[c]);
  }
  __syncthreads();                 // all S reads done
  #pragma unroll
  for (int c=0;c<16;c++) sh[lane][cb+c] = acc[c];   // sh := agg
  __syncthreads();

  // ---- P1: hid = gelu(h@U1a + agg@U1b + b1) ----
  #pragma unroll
  for (int c=0;c<16;c++) acc2[c] = wf[UB1 + l*64 + cb + c];
  const float* u1l = wf + UW1 + l*8192;
  #pragma unroll 2
  for (int j=0;j<64;j++){
    float hj = hh[lane][j];
    float aj = sh[lane][j];
    const float* wra = u1l + j*64 + cb;
    const float* wrb = u1l + (64+j)*64 + cb;
    #pragma unroll
    for (int c=0;c<16;c++) acc2[c] = fmaf(hj, wra[c], fmaf(aj, wrb[c], acc2[c]));
  }
  #pragma unroll
  for (int c=0;c<16;c++) acc2[c] = gelu_t(acc2[c]);
  __syncthreads();                 // all agg reads done
  #pragma unroll
  for (int c=0;c<16;c++) sh[lane][cb+c] = acc2[c];  // sh := hid
  __syncthreads();

  // ---- P2: upd = hid@U2 + b2; residual (from hh); LN ----
  const float* u2l = wf + UW2 + l*4096;
  #pragma unroll
  for (int c=0;c<16;c++) acc[c] = wf[UB2 + l*64 + cb + c];
  #pragma unroll 4
  for (int j=0;j<64;j++){
    float xj = sh[lane][j];
    const float* wr = u2l + j*64 + cb;
    #pragma unroll
    for (int c=0;c<16;c++) acc[c] = fmaf(xj, wr[c], acc[c]);
  }
  #pragma unroll
  for (int c=0;c<16;c++) acc[c] += hh[lane][cb+c];
  float s1 = 0.f, s2 = 0.f;
  #pragma unroll
  for (int c=0;c<16;c++){ s1 += acc[c]; s2 = fmaf(acc[c], acc[c], s2); }
  part[wv][lane] = make_float2(s1, s2);
  __syncthreads();                 // part ready; also: all sh/hh reads done
  float m = 0.f, v2 = 0.f;
  #pragma unroll
  for (int ww=0; ww<4; ww++){ float2 pp = part[ww][lane]; m += pp.x; v2 += pp.y; }
  m *= (1.0f/64.0f);
  v2 = v2*(1.0f/64.0f) - m*m;
  float inv = frsq(v2 + 1e-5f);
  float hp[16];
  #pragma unroll
  for (int c=0;c<16;c++)
    hp[c] = (acc[c]-m)*inv*wf[LNG + l*64 + cb + c] + wf[LNB + l*64 + cb + c];

  if (LAST){
    float po = 0.f;
    #pragma unroll
    for (int c=0;c<16;c++) po = fmaf(hp[c], wf[OUTW + cb + c], po);
    __syncthreads();
    part[wv][lane].x = po;
    __syncthreads();
    if (wv == 0){
      float o = wf[OUTB] + part[0][lane].x + part[1][lane].x + part[2][lane].x + part[3][lane].x;
      stf(dout, obase + node, o, *flag);
    }
  } else {
    float* hw = h + (size_t)node*64 + cb;
    #pragma unroll
    for (int q=0;q<4;q++)
      *(float4*)(hw + 4*q) = make_float4(hp[4*q],hp[4*q+1],hp[4*q+2],hp[4*q+3]);
    #pragma unroll
    for (int c=0;c<16;c++) sh[lane][cb+c] = hp[c];  // sh := h'
    __syncthreads();
    // ---- P3: P' = h'@W1a(l+1), Q' = h'@W1b(l+1) ----
    const float* w1n = wf + MW1 + (l+1)*8320;
    #pragma unroll
    for (int c=0;c<16;c++){ acc[c] = 0.f; acc2[c] = 0.f; }
    #pragma unroll 2
    for (int j=0;j<64;j++){
      float xj = sh[lane][j];
      const float* wp = w1n + j*64 + cb;
      const float* wq = w1n + (64+j)*64 + cb;
      #pragma unroll
      for (int c=0;c<16;c++){
        acc[c]  = fmaf(xj, wp[c], acc[c]);
        acc2[c] = fmaf(xj, wq[c], acc2[c]);
      }
    }
    float* prow = PS + (size_t)node*64 + cb;
    float* qrow = Qb + (size_t)node*64 + cb;
    #pragma unroll
    for (int q=0;q<4;q++){
      *(float4*)(prow + 4*q) = make_float4(acc[4*q],acc[4*q+1],acc[4*q+2],acc[4*q+3]);
      *(float4*)(qrow + 4*q) = make_float4(acc2[4*q],acc2[4*q+1],acc2[4*q+2],acc2[4*q+3]);
    }
  }
}

// ---------------- host launcher ----------------
extern "C" void kernel_launch(void* const* d_in, const int* in_sizes, int n_in,
                              void* d_out, int out_size, void* d_ws, size_t ws_size,
                              hipStream_t stream)
{
  if (ws_size < (size_t)WS_NEED_FLOATS * 4ull) {
    k_encode<<<(OUTTOT+255)/256, 256, 0, stream>>>((bf16*)d_out, (float)ws_size);
    return;
  }

  float* ws   = (float*)d_ws;
  float* h    = ws + H_OFF;
  float* PS   = ws + PS_OFF;
  float* Qb   = ws + Q_OFF;
  float* nfw  = ws + NF_OFF;
  float4* nf  = (float4*)nfw;
  float* wf   = ws + WF_OFF;
  int*  flag  = (int*)(ws + FLAG_OFF);

  k_sniff<<<1, 64, 0, stream>>>(d_in[1], flag);

  WArgs wa;
  static const int cnts[18] = {64,64,24960,192,12288,192,1344,192,192,3,24576,192,12288,192,192,192,64,1};
  static const int offs[18] = {IN_W,IN_B,MW1,MB1,MW2,MB2,GW1,GB1,GW2,GB2,UW1,UB1,UW2,UB2,LNG,LNB,OUTW,OUTB};
  for (int k = 0; k < 18; k++){ wa.p[k] = d_in[4+k]; wa.cnt[k] = cnts[k]; wa.off[k] = offs[k]; }
  k_conv<<<dim3(98,18), 256, 0, stream>>>(wa, wf, flag);

  for (int b = 0; b < NB; b++){
    k_feat<<<256, 256, 0, stream>>>(d_in[1], (long)b*NPN, flag, nf);
    k_init<<<1024, 256, 0, stream>>>(nf, h, PS, Qb, wf);

    for (int l = 0; l < 3; l++){
      k_B<<<16384, 256, 0, stream>>>(PS, Qb, nf, nfw, wf, l,
          d_out, (long)NNODES + (long)l*NE + (long)b*EPB, flag);
      if (l < 2)
        k_C<0><<<1024, 256, 0, stream>>>(PS, h, Qb, nf, wf, l, d_out, (long)b*NPN, flag);
      else
        k_C<1><<<1024, 256, 0, stream>>>(PS, h, Qb, nf, wf, l, d_out, (long)b*NPN, flag);
    }
  }
}